// Round 1
// baseline (299.861 us; speedup 1.0000x reference)
//
#include <hip/hip_runtime.h>
#include <cstdint>
#include <cstddef>

typedef __bf16 bf16;
typedef bf16 bf16x4 __attribute__((ext_vector_type(4)));
typedef bf16 bf16x8 __attribute__((ext_vector_type(8)));
typedef float f32x4 __attribute__((ext_vector_type(4)));

// async global->LDS, 16B per lane. LDS dest must equal wave-uniform base + lane*16.
__device__ __forceinline__ void gload_lds16(const bf16* g, bf16* l) {
    __builtin_amdgcn_global_load_lds(
        (__attribute__((address_space(1))) void*)(uintptr_t)(g),
        (__attribute__((address_space(3))) void*)(l),
        16, 0, 0);
}

// ---------------- fp32 -> bf16 convert ----------------
__global__ __launch_bounds__(256) void cvt_kernel(const float* __restrict__ in,
                                                  bf16* __restrict__ out, int n4) {
    int i = blockIdx.x * 256 + threadIdx.x;
    if (i >= n4) return;
    float4 v = ((const float4*)in)[i];
    bf16x4 o;
    o[0] = (bf16)v.x; o[1] = (bf16)v.y; o[2] = (bf16)v.z; o[3] = (bf16)v.w;
    *(bf16x4*)(out + (size_t)i * 4) = o;
}

// ---------------- rope cos/sin table: [w (1024)][j (32)] ----------------
__global__ __launch_bounds__(256) void rope_tab_kernel(float2* __restrict__ t) {
    int i = blockIdx.x * 256 + threadIdx.x;   // 0..32767
    int w = i >> 5, j = i & 31;
    // inv_freq = 10000^(-j/32) = 2^(-j*log2(10000)/32)
    float inv = exp2f(-(float)j * (13.287712379549449f / 32.0f));
    float a = (float)w * inv;
    t[i] = make_float2(cosf(a), sinf(a));
}

// ---------------- BT-GEMM: C(M,N) = A(M,K) * B(N,K)^T, M=N=K=1024 per slice ----
// grid (8 ntiles, 8 mtiles, 8 slices), block 256. B is per-channel (slice&3).
template <bool F32OUT>
__global__ void __launch_bounds__(256) gemm_bt(const bf16* __restrict__ A,
                                               const bf16* __restrict__ B,
                                               void* __restrict__ Cout) {
    __shared__ alignas(16) bf16 As[128 * 64];
    __shared__ alignas(16) bf16 Bs[128 * 64];
    const int tid = threadIdx.x, lane = tid & 63, wave = tid >> 6;
    const int l15 = lane & 15, quad = lane >> 4;
    const int s = blockIdx.z;
    const bf16* Ab = A + ((size_t)s << 20) + (size_t)blockIdx.y * 128 * 1024;
    const bf16* Bb = B + ((size_t)(s & 3) << 20) + (size_t)blockIdx.x * 128 * 1024;
    const int wm = (wave >> 1) * 64, wn = (wave & 1) * 64;

    const f32x4 fzero = {0.f, 0.f, 0.f, 0.f};
    f32x4 acc[4][4];
    for (int i = 0; i < 4; ++i)
        for (int j = 0; j < 4; ++j) acc[i][j] = fzero;

    const int sr = wave * 8 + (lane >> 3);   // staging row base
    const int sc = (lane & 7) * 8;           // staging col (bf16 elems)

    for (int kt = 0; kt < 16; ++kt) {
        __syncthreads();
        for (int it = 0; it < 4; ++it) {
            int r = it * 32 + sr;
            gload_lds16(Ab + (size_t)r * 1024 + kt * 64 + sc, As + r * 64 + sc);
            gload_lds16(Bb + (size_t)r * 1024 + kt * 64 + sc, Bs + r * 64 + sc);
        }
        __syncthreads();
        for (int kk = 0; kk < 2; ++kk) {
            bf16x8 af[4], bfr[4];
            for (int i = 0; i < 4; ++i)
                af[i] = *(const bf16x8*)(As + (wm + i * 16 + l15) * 64 + kk * 32 + quad * 8);
            for (int j = 0; j < 4; ++j)
                bfr[j] = *(const bf16x8*)(Bs + (wn + j * 16 + l15) * 64 + kk * 32 + quad * 8);
            for (int i = 0; i < 4; ++i)
                for (int j = 0; j < 4; ++j)
                    acc[i][j] = __builtin_amdgcn_mfma_f32_16x16x32_bf16(af[i], bfr[j],
                                                                        acc[i][j], 0, 0, 0);
        }
    }
    // epilogue: C/D layout col=lane&15 (=n), row=quad*4+reg (=m)
    size_t cbase = ((size_t)s << 20) + (size_t)blockIdx.y * 128 * 1024 + blockIdx.x * 128;
    for (int i = 0; i < 4; ++i)
        for (int j = 0; j < 4; ++j) {
            int m = wm + i * 16 + quad * 4;
            int n = wn + j * 16 + l15;
            for (int r = 0; r < 4; ++r) {
                float v = acc[i][j][r];
                if (F32OUT)
                    ((float*)Cout)[cbase + (size_t)(m + r) * 1024 + n] = v;
                else
                    ((bf16*)Cout)[cbase + (size_t)(m + r) * 1024 + n] = (bf16)v;
            }
        }
}

// ---------------- conv(1x3 along w) + bias, then RoPE + transpose ----------------
// in : Yb[s][h][w] bf16. out: Pb[s][h][w] bf16 (V, d-major), Qt[s][w][h] bf16 (roped Q=K)
__global__ void __launch_bounds__(256) conv_rope_kernel(
    const bf16* __restrict__ Yb, const float* __restrict__ wconv,
    const float* __restrict__ bconv, bf16* __restrict__ Qt,
    bf16* __restrict__ Pb, const float2* __restrict__ rtab) {
    __shared__ float Pt[32][33];
    const int s = blockIdx.z, cch = s & 3;
    const int h0 = blockIdx.y * 32, w0 = blockIdx.x * 32;
    const bf16* Y = Yb + ((size_t)s << 20);
    const float k0 = wconv[cch * 3], k1 = wconv[cch * 3 + 1], k2 = wconv[cch * 3 + 2];
    const float bias = bconv[cch];
    const int tw = threadIdx.x & 31, th = threadIdx.x >> 5;

    for (int hh = th; hh < 32; hh += 8) {
        int h = h0 + hh, w = w0 + tw;
        size_t rowb = (size_t)h << 10;
        float ym = (w > 0) ? (float)Y[rowb + w - 1] : 0.f;
        float yc = (float)Y[rowb + w];
        float yp = (w < 1023) ? (float)Y[rowb + w + 1] : 0.f;
        float p = fmaf(k0, ym, fmaf(k1, yc, fmaf(k2, yp, bias)));
        Pt[hh][tw] = p;
        Pb[((size_t)s << 20) + rowb + w] = (bf16)p;
    }
    __syncthreads();
    const int hh = tw;
    const int h = h0 + hh;
    const int d = h & 127;
    for (int ww = th; ww < 32; ww += 8) {
        int w = w0 + ww;
        float p = Pt[hh][ww];
        float q;
        if (d < 64) {
            float2 cs = rtab[(w << 5) + (d >> 1)];
            float pp = Pt[hh ^ 1][ww];
            q = (d & 1) ? fmaf(p, cs.x, pp * cs.y) : fmaf(p, cs.x, -pp * cs.y);
        } else {
            q = p;
        }
        Qt[((size_t)s << 20) + ((size_t)w << 10) + h] = (bf16)q;
    }
}

// ---------------- fused flash attention ----------------
// grid (8 qtiles, 8 heads, 8 slices), block 256 (4 waves). Q-tile 128, K-tile 64.
// Qt[s][w][h] serves as Q and K; Pb[s][h][w] is V in d-major layout.
// out: AO[s][h][w] bf16  (h = head*128 + d, w = query pos)
__global__ void __launch_bounds__(256, 2) attn_kernel(const bf16* __restrict__ Qt,
                                                      const bf16* __restrict__ Pb,
                                                      bf16* __restrict__ AO) {
    __shared__ alignas(16) char smem[49152];
    bf16* Ks = (bf16*)smem;              // 64 x 128  (16 KB)
    bf16* Vs = (bf16*)(smem + 16384);    // 128(d) x 64(key)  (16 KB)
    bf16* Ps = (bf16*)(smem + 32768);    // 4 waves x 32 x 64 (16 KB)

    const int tid = threadIdx.x, lane = tid & 63, wave = tid >> 6;
    const int l15 = lane & 15, quad = lane >> 4;
    const int s = blockIdx.z, head = blockIdx.y, q0 = blockIdx.x * 128;
    const bf16* Qg = Qt + ((size_t)s << 20);
    const bf16* Pg = Pb + ((size_t)s << 20);

    // ---- stage Q tile (128x128) across Ks+Vs, read frags to registers ----
    bf16* Qs = (bf16*)smem;
    for (int it = 0; it < 8; ++it) {
        int r = it * 16 + wave * 4 + quad;
        gload_lds16(Qg + (size_t)(q0 + r) * 1024 + head * 128 + l15 * 8,
                    Qs + r * 128 + l15 * 8);
    }
    __syncthreads();
    bf16x8 qf[2][4];
    for (int i = 0; i < 2; ++i)
        for (int kk = 0; kk < 4; ++kk)
            qf[i][kk] = *(const bf16x8*)(Qs + (wave * 32 + i * 16 + l15) * 128 +
                                         kk * 32 + quad * 8);

    const f32x4 fzero = {0.f, 0.f, 0.f, 0.f};
    f32x4 Oacc[2][8];
    for (int i = 0; i < 2; ++i)
        for (int j = 0; j < 8; ++j) Oacc[i][j] = fzero;
    float mrow[2][4], lrow[2][4];
    for (int i = 0; i < 2; ++i)
        for (int r = 0; r < 4; ++r) { mrow[i][r] = -1e30f; lrow[i][r] = 0.f; }

    const float cexp = 1.4426950408889634f / 32.0f;   // log2(e)/sqrt(1024)
    bf16* myP = Ps + wave * (32 * 64);

    for (int kt = 0; kt < 16; ++kt) {
        __syncthreads();
        for (int it = 0; it < 4; ++it) {
            int rk = it * 16 + wave * 4 + quad;
            gload_lds16(Qg + (size_t)(kt * 64 + rk) * 1024 + head * 128 + l15 * 8,
                        Ks + rk * 128 + l15 * 8);
            int rv = it * 32 + wave * 8 + (lane >> 3);
            int cv = (lane & 7) * 8;
            gload_lds16(Pg + (size_t)(head * 128 + rv) * 1024 + kt * 64 + cv,
                        Vs + rv * 64 + cv);
        }
        __syncthreads();

        // S = Q * K^T  (32 q-rows per wave x 64 keys)
        f32x4 sacc[2][4];
        for (int i = 0; i < 2; ++i)
            for (int j = 0; j < 4; ++j) sacc[i][j] = fzero;
        for (int kk = 0; kk < 4; ++kk) {
            bf16x8 kf[4];
            for (int j = 0; j < 4; ++j)
                kf[j] = *(const bf16x8*)(Ks + (j * 16 + l15) * 128 + kk * 32 + quad * 8);
            for (int i = 0; i < 2; ++i)
                for (int j = 0; j < 4; ++j)
                    sacc[i][j] = __builtin_amdgcn_mfma_f32_16x16x32_bf16(qf[i][kk], kf[j],
                                                                         sacc[i][j], 0, 0, 0);
        }
        // online softmax (exponent scale folded: softmax(S/32))
        for (int i = 0; i < 2; ++i)
            for (int r = 0; r < 4; ++r) {
                float mx = sacc[i][0][r];
                for (int j = 1; j < 4; ++j) mx = fmaxf(mx, sacc[i][j][r]);
                mx = fmaxf(mx, __shfl_xor(mx, 1));
                mx = fmaxf(mx, __shfl_xor(mx, 2));
                mx = fmaxf(mx, __shfl_xor(mx, 4));
                mx = fmaxf(mx, __shfl_xor(mx, 8));
                float mnew = fmaxf(mrow[i][r], mx);
                float alpha = exp2f((mrow[i][r] - mnew) * cexp);
                mrow[i][r] = mnew;
                float rs = 0.f;
                for (int j = 0; j < 4; ++j) {
                    float p = exp2f((sacc[i][j][r] - mnew) * cexp);
                    sacc[i][j][r] = p;
                    rs += p;
                }
                rs += __shfl_xor(rs, 1);
                rs += __shfl_xor(rs, 2);
                rs += __shfl_xor(rs, 4);
                rs += __shfl_xor(rs, 8);
                lrow[i][r] = lrow[i][r] * alpha + rs;
                for (int j = 0; j < 8; ++j) Oacc[i][j][r] *= alpha;
            }
        // P-tilde: C-layout -> LDS (wave-private) -> A-layout frags
        for (int i = 0; i < 2; ++i)
            for (int j = 0; j < 4; ++j)
                for (int r = 0; r < 4; ++r) {
                    int row = i * 16 + quad * 4 + r;
                    int col = j * 16 + l15;
                    myP[row * 64 + col] = (bf16)sacc[i][j][r];
                }
        // O += P * V
        for (int kk2 = 0; kk2 < 2; ++kk2) {
            bf16x8 pf[2];
            for (int i = 0; i < 2; ++i)
                pf[i] = *(const bf16x8*)(myP + (i * 16 + l15) * 64 + kk2 * 32 + quad * 8);
            for (int j = 0; j < 8; ++j) {
                bf16x8 vf = *(const bf16x8*)(Vs + (j * 16 + l15) * 64 + kk2 * 32 + quad * 8);
                for (int i = 0; i < 2; ++i)
                    Oacc[i][j] = __builtin_amdgcn_mfma_f32_16x16x32_bf16(pf[i], vf,
                                                                         Oacc[i][j], 0, 0, 0);
            }
        }
    }

    // ---- epilogue: normalize, transpose through LDS, coalesced store ----
    __syncthreads();
    bf16* Ot = (bf16*)smem;   // [d (128)][q (128)] stride 136, 34816 B (< 48 KB)
    float rinv[2][4];
    for (int i = 0; i < 2; ++i)
        for (int r = 0; r < 4; ++r) rinv[i][r] = 1.0f / lrow[i][r];
    for (int i = 0; i < 2; ++i)
        for (int j = 0; j < 8; ++j)
            for (int r = 0; r < 4; ++r) {
                int q = wave * 32 + i * 16 + quad * 4 + r;
                int d = j * 16 + l15;
                Ot[d * 136 + q] = (bf16)(Oacc[i][j][r] * rinv[i][r]);
            }
    __syncthreads();
    bf16* AOg = AO + ((size_t)s << 20);
    for (int it = 0; it < 8; ++it) {
        int d = it * 16 + (tid >> 4);
        int qc = (tid & 15) * 8;
        bf16x8 v = *(const bf16x8*)(Ot + d * 136 + qc);
        *(bf16x8*)(AOg + (size_t)(head * 128 + d) * 1024 + q0 + qc) = v;
    }
}

// ---------------- launch ----------------
extern "C" void kernel_launch(void* const* d_in, const int* in_sizes, int n_in,
                              void* d_out, int out_size, void* d_ws, size_t ws_size,
                              hipStream_t stream) {
    const float* x  = (const float*)d_in[0];
    const float* wq = (const float*)d_in[1];
    const float* wc = (const float*)d_in[2];
    const float* bc = (const float*)d_in[3];
    const float* wo = (const float*)d_in[4];
    float* out = (float*)d_out;

    char* ws = (char*)d_ws;
    bf16* xb   = (bf16*)ws;                      // 16 MiB (x bf16; later aliased as AO)
    bf16* wqb  = (bf16*)(ws + (16u << 20));      //  8 MiB
    bf16* wob  = (bf16*)(ws + (24u << 20));      //  8 MiB
    bf16* Yb   = (bf16*)(ws + (32u << 20));      // 16 MiB  proj output (h,o)
    bf16* Qt   = (bf16*)(ws + (48u << 20));      // 16 MiB  roped, [s][w][h]
    bf16* Pb   = (bf16*)(ws + (64u << 20));      // 16 MiB  conv out,  [s][h][w]
    float2* rtab = (float2*)(ws + (80u << 20));  // 256 KiB cos/sin table
    bf16* AO   = xb;                             // alias: x consumed after gemm1

    cvt_kernel<<<8192, 256, 0, stream>>>(x, xb, 2097152);
    cvt_kernel<<<4096, 256, 0, stream>>>(wq, wqb, 1048576);
    cvt_kernel<<<4096, 256, 0, stream>>>(wo, wob, 1048576);
    rope_tab_kernel<<<128, 256, 0, stream>>>(rtab);

    gemm_bt<false><<<dim3(8, 8, 8), 256, 0, stream>>>(xb, wqb, Yb);
    conv_rope_kernel<<<dim3(32, 32, 8), 256, 0, stream>>>(Yb, wc, bc, Qt, Pb, rtab);
    attn_kernel<<<dim3(8, 8, 8), 256, 0, stream>>>(Qt, Pb, AO);
    gemm_bt<true><<<dim3(8, 8, 8), 256, 0, stream>>>(AO, wob, out);
}

// Round 3
// 233.111 us; speedup vs baseline: 1.2863x; 1.2863x over previous
//
#include <hip/hip_runtime.h>
#include <cstdint>
#include <cstddef>

typedef __bf16 bf16;
typedef bf16 bf16x4 __attribute__((ext_vector_type(4)));
typedef bf16 bf16x8 __attribute__((ext_vector_type(8)));
typedef float f32x4 __attribute__((ext_vector_type(4)));

// async global->LDS, 16B per lane. LDS dest must equal wave-uniform base + lane*16.
__device__ __forceinline__ void gload_lds16(const bf16* g, bf16* l) {
    __builtin_amdgcn_global_load_lds(
        (__attribute__((address_space(1))) void*)(uintptr_t)(g),
        (__attribute__((address_space(3))) void*)(l),
        16, 0, 0);
}

// ---------------- fp32 -> bf16 convert ----------------
__global__ __launch_bounds__(256) void cvt_kernel(const float* __restrict__ in,
                                                  bf16* __restrict__ out, int n4) {
    int i = blockIdx.x * 256 + threadIdx.x;
    if (i >= n4) return;
    float4 v = ((const float4*)in)[i];
    bf16x4 o;
    o[0] = (bf16)v.x; o[1] = (bf16)v.y; o[2] = (bf16)v.z; o[3] = (bf16)v.w;
    *(bf16x4*)(out + (size_t)i * 4) = o;
}

// ---------------- rope cos/sin table: [w (1024)][j (32)] ----------------
__global__ __launch_bounds__(256) void rope_tab_kernel(float2* __restrict__ t) {
    int i = blockIdx.x * 256 + threadIdx.x;   // 0..32767
    int w = i >> 5, j = i & 31;
    float inv = exp2f(-(float)j * (13.287712379549449f / 32.0f));
    float a = (float)w * inv;
    t[i] = make_float2(cosf(a), sinf(a));
}

// ---------------- BT-GEMM: C(M,N) = A(M,K) * B(N,K)^T, M=N=K=1024 per slice ----
template <bool F32OUT>
__global__ void __launch_bounds__(256) gemm_bt(const bf16* __restrict__ A,
                                               const bf16* __restrict__ B,
                                               void* __restrict__ Cout) {
    __shared__ alignas(16) bf16 As[128 * 64];
    __shared__ alignas(16) bf16 Bs[128 * 64];
    const int tid = threadIdx.x, lane = tid & 63, wave = tid >> 6;
    const int l15 = lane & 15, quad = lane >> 4;
    const int s = blockIdx.z;
    const bf16* Ab = A + ((size_t)s << 20) + (size_t)blockIdx.y * 128 * 1024;
    const bf16* Bb = B + ((size_t)(s & 3) << 20) + (size_t)blockIdx.x * 128 * 1024;
    const int wm = (wave >> 1) * 64, wn = (wave & 1) * 64;

    const f32x4 fzero = {0.f, 0.f, 0.f, 0.f};
    f32x4 acc[4][4];
    for (int i = 0; i < 4; ++i)
        for (int j = 0; j < 4; ++j) acc[i][j] = fzero;

    const int sr = wave * 8 + (lane >> 3);
    const int sc = (lane & 7) * 8;

    for (int kt = 0; kt < 16; ++kt) {
        __syncthreads();
        for (int it = 0; it < 4; ++it) {
            int r = it * 32 + sr;
            gload_lds16(Ab + (size_t)r * 1024 + kt * 64 + sc, As + r * 64 + sc);
            gload_lds16(Bb + (size_t)r * 1024 + kt * 64 + sc, Bs + r * 64 + sc);
        }
        __syncthreads();
        for (int kk = 0; kk < 2; ++kk) {
            bf16x8 af[4], bfr[4];
            for (int i = 0; i < 4; ++i)
                af[i] = *(const bf16x8*)(As + (wm + i * 16 + l15) * 64 + kk * 32 + quad * 8);
            for (int j = 0; j < 4; ++j)
                bfr[j] = *(const bf16x8*)(Bs + (wn + j * 16 + l15) * 64 + kk * 32 + quad * 8);
            for (int i = 0; i < 4; ++i)
                for (int j = 0; j < 4; ++j)
                    acc[i][j] = __builtin_amdgcn_mfma_f32_16x16x32_bf16(af[i], bfr[j],
                                                                        acc[i][j], 0, 0, 0);
        }
    }
    size_t cbase = ((size_t)s << 20) + (size_t)blockIdx.y * 128 * 1024 + blockIdx.x * 128;
    for (int i = 0; i < 4; ++i)
        for (int j = 0; j < 4; ++j) {
            int m = wm + i * 16 + quad * 4;
            int n = wn + j * 16 + l15;
            for (int r = 0; r < 4; ++r) {
                float v = acc[i][j][r];
                if (F32OUT)
                    ((float*)Cout)[cbase + (size_t)(m + r) * 1024 + n] = v;
                else
                    ((bf16*)Cout)[cbase + (size_t)(m + r) * 1024 + n] = (bf16)v;
            }
        }
}

// ---------------- conv(1x3 along w) + bias, RoPE, emit fragment-layout Q/V ----
// in : Yb[s][h][w] bf16.
// out: Vhat[s][head][wchunk(128)][d(128)][8w]  (V, B-operand frag layout for PV)
//      Qhat[s][head][dchunk(16)][w(1024)][8d]  (roped Q=K, A/B frag layout for QK)
__global__ void __launch_bounds__(256) conv_rope_kernel(
    const bf16* __restrict__ Yb, const float* __restrict__ wconv,
    const float* __restrict__ bconv, bf16* __restrict__ Qhat,
    bf16* __restrict__ Vhat, const float2* __restrict__ rtab) {
    __shared__ float Pt[32][260];
    const int s = blockIdx.z, cch = s & 3;
    const int h0 = blockIdx.y * 32, w0 = blockIdx.x * 256;
    const bf16* Y = Yb + ((size_t)s << 20);
    const float k0 = wconv[cch * 3], k1 = wconv[cch * 3 + 1], k2 = wconv[cch * 3 + 2];
    const float bias = bconv[cch];

    // phase 1: conv 8 consecutive w per thread (4 iters cover 32h x 256w tile)
    for (int it = 0; it < 4; ++it) {
        const int hh = threadIdx.x >> 3;
        const int wseg = (threadIdx.x & 7) + it * 8;   // 0..31
        const int h = h0 + hh, w = w0 + wseg * 8;
        const bf16* yrow = Y + ((size_t)h << 10);
        bf16x8 yv = *(const bf16x8*)(yrow + w);
        float yc[10];
        yc[0] = (w > 0) ? (float)yrow[w - 1] : 0.f;
        for (int i = 0; i < 8; ++i) yc[i + 1] = (float)yv[i];
        yc[9] = (w + 8 < 1024) ? (float)yrow[w + 8] : 0.f;
        bf16x8 pb;
        for (int i = 0; i < 8; ++i) {
            float p = fmaf(k0, yc[i], fmaf(k1, yc[i + 1], fmaf(k2, yc[i + 2], bias)));
            Pt[hh][wseg * 8 + i] = p;
            pb[i] = (bf16)p;
        }
        const int head = h >> 7, d = h & 127;
        *(bf16x8*)(Vhat + ((((size_t)s * 8 + head) * 128 + (w >> 3)) << 10) + d * 8) = pb;
    }
    __syncthreads();
    // phase 2: rope 8 consecutive d per thread at fixed w, write Qhat
    {
        const int dcb = threadIdx.x >> 6;            // 0..3 (dchunk within tile)
        const int head = h0 >> 7;
        const int d0 = (h0 & 127) + dcb * 8;         // global d of chunk start
        const int hb0 = dcb * 8;
        for (int it = 0; it < 4; ++it) {
            const int wl = (threadIdx.x & 63) + it * 64;
            const int w = w0 + wl;
            float q[8];
            if (d0 < 64) {
                for (int j = 0; j < 8; j += 2) {
                    float2 cs = rtab[(w << 5) + ((d0 + j) >> 1)];
                    float a = Pt[hb0 + j][wl], b = Pt[hb0 + j + 1][wl];
                    q[j]     = fmaf(a, cs.x, -b * cs.y);
                    q[j + 1] = fmaf(b, cs.x,  a * cs.y);
                }
            } else {
                for (int j = 0; j < 8; ++j) q[j] = Pt[hb0 + j][wl];
            }
            bf16x8 qb;
            for (int j = 0; j < 8; ++j) qb[j] = (bf16)q[j];
            *(bf16x8*)(Qhat + ((((size_t)s * 8 + head) * 16 + (d0 >> 3)) << 13) +
                       (size_t)w * 8) = qb;
        }
    }
}

// ---------------- fused flash attention (no-max softmax, frag-layout LDS) ------
// grid (8,8,8) flat-decoded: sh = b&63 (s,head), qtile = b>>6  [XCD locality]
// out: AO[s][h][w] bf16  (h = head*128 + d, w = query pos)
__global__ void __launch_bounds__(256, 2) attn_kernel(const bf16* __restrict__ Qhat,
                                                      const bf16* __restrict__ Vhat,
                                                      bf16* __restrict__ AO) {
    __shared__ alignas(16) char smem[51200];
    bf16* Ks = (bf16*)smem;              // [16 dc][64 key][8]  16 KB
    bf16* Vs = (bf16*)(smem + 16384);    // [8 wc][128 d][8]    16 KB
    bf16* Ps = (bf16*)(smem + 32768);    // 4 waves x 32 x 72   18 KB

    const int tid = threadIdx.x, lane = tid & 63, wave = tid >> 6;
    const int l15 = lane & 15, quad = lane >> 4;
    const int b = blockIdx.x + blockIdx.y * 8 + blockIdx.z * 64;
    const int sh = b & 63, qtile = b >> 6;
    const int s = sh >> 3, head = sh & 7, q0 = qtile * 128;
    const bf16* Qg = Qhat + (size_t)sh * 131072;
    const bf16* Vg = Vhat + (size_t)sh * 131072;

    // Q frags straight from global (A-operand layout)
    bf16x8 qf[2][4];
    for (int i = 0; i < 2; ++i)
        for (int kk = 0; kk < 4; ++kk)
            qf[i][kk] = *(const bf16x8*)(Qg + (size_t)(kk * 4 + quad) * 8192 +
                                         (size_t)(q0 + wave * 32 + i * 16 + l15) * 8);

    const f32x4 fzero = {0.f, 0.f, 0.f, 0.f};
    f32x4 Oacc[2][8];
    for (int i = 0; i < 2; ++i)
        for (int j = 0; j < 8; ++j) Oacc[i][j] = fzero;
    float lsum[2][4];
    for (int i = 0; i < 2; ++i)
        for (int r = 0; r < 4; ++r) lsum[i][r] = 0.f;

    const float cexp = 1.4426950408889634f / 32.0f;   // log2(e)/sqrt(1024)
    bf16* myP = Ps + wave * (32 * 72);

    for (int kt = 0; kt < 16; ++kt) {
        __syncthreads();
        for (int t = 0; t < 4; ++t) {
            int dc = wave * 4 + t;
            gload_lds16(Qg + (size_t)dc * 8192 + (size_t)(kt * 64 + lane) * 8,
                        Ks + (dc * 64 + lane) * 8);
            int wc = dc >> 1, half = dc & 1;
            gload_lds16(Vg + (size_t)(kt * 8 + wc) * 1024 + (size_t)(half * 64 + lane) * 8,
                        Vs + (wc * 128 + half * 64 + lane) * 8);
        }
        __syncthreads();

        // S = Q * K^T
        f32x4 sacc[2][4];
        for (int i = 0; i < 2; ++i)
            for (int j = 0; j < 4; ++j) sacc[i][j] = fzero;
        for (int kk = 0; kk < 4; ++kk) {
            bf16x8 kf[4];
            for (int j = 0; j < 4; ++j)
                kf[j] = *(const bf16x8*)(Ks + ((kk * 4 + quad) * 64 + j * 16 + l15) * 8);
            for (int i = 0; i < 2; ++i)
                for (int j = 0; j < 4; ++j)
                    sacc[i][j] = __builtin_amdgcn_mfma_f32_16x16x32_bf16(qf[i][kk], kf[j],
                                                                         sacc[i][j], 0, 0, 0);
        }
        // exp (fixed max=0), per-lane partial sums, P-tilde to LDS (A-frag source)
        for (int i = 0; i < 2; ++i)
            for (int r = 0; r < 4; ++r) {
                float acc = 0.f;
                for (int j = 0; j < 4; ++j) {
                    float p = exp2f(sacc[i][j][r] * cexp);
                    myP[(i * 16 + quad * 4 + r) * 72 + j * 16 + l15] = (bf16)p;
                    acc += p;
                }
                lsum[i][r] += acc;
            }
        // O += P * V
        for (int kk2 = 0; kk2 < 2; ++kk2) {
            bf16x8 pf[2];
            for (int i = 0; i < 2; ++i)
                pf[i] = *(const bf16x8*)(myP + (i * 16 + l15) * 72 + kk2 * 32 + quad * 8);
            for (int j = 0; j < 8; ++j) {
                bf16x8 vf = *(const bf16x8*)(Vs + ((kk2 * 4 + quad) * 128 + j * 16 + l15) * 8);
                for (int i = 0; i < 2; ++i)
                    Oacc[i][j] = __builtin_amdgcn_mfma_f32_16x16x32_bf16(pf[i], vf,
                                                                         Oacc[i][j], 0, 0, 0);
            }
        }
    }

    // ---- epilogue: reduce row sums, normalize, transpose, coalesced store ----
    float rinv[2][4];
    for (int i = 0; i < 2; ++i)
        for (int r = 0; r < 4; ++r) {
            float v = lsum[i][r];
            v += __shfl_xor(v, 1);
            v += __shfl_xor(v, 2);
            v += __shfl_xor(v, 4);
            v += __shfl_xor(v, 8);
            rinv[i][r] = 1.0f / v;
        }
    __syncthreads();
    bf16* Ot = (bf16*)smem;   // [d(128)][q(128)] stride 136
    for (int i = 0; i < 2; ++i)
        for (int j = 0; j < 8; ++j)
            for (int r = 0; r < 4; ++r) {
                int q = wave * 32 + i * 16 + quad * 4 + r;
                int d = j * 16 + l15;
                Ot[d * 136 + q] = (bf16)(Oacc[i][j][r] * rinv[i][r]);
            }
    __syncthreads();
    bf16* AOg = AO + ((size_t)s << 20);
    for (int it = 0; it < 8; ++it) {
        int d = it * 16 + (tid >> 4);
        int qc = (tid & 15) * 8;
        bf16x8 v = *(const bf16x8*)(Ot + d * 136 + qc);
        *(bf16x8*)(AOg + (size_t)(head * 128 + d) * 1024 + q0 + qc) = v;
    }
}

// ---------------- launch ----------------
extern "C" void kernel_launch(void* const* d_in, const int* in_sizes, int n_in,
                              void* d_out, int out_size, void* d_ws, size_t ws_size,
                              hipStream_t stream) {
    const float* x  = (const float*)d_in[0];
    const float* wq = (const float*)d_in[1];
    const float* wc = (const float*)d_in[2];
    const float* bc = (const float*)d_in[3];
    const float* wo = (const float*)d_in[4];
    float* out = (float*)d_out;

    char* ws = (char*)d_ws;
    bf16* xb   = (bf16*)ws;                      // 16 MiB (x bf16; later aliased as AO)
    bf16* wqb  = (bf16*)(ws + (16u << 20));      //  8 MiB
    bf16* wob  = (bf16*)(ws + (24u << 20));      //  8 MiB
    bf16* Yb   = (bf16*)(ws + (32u << 20));      // 16 MiB  proj output
    bf16* Qhat = (bf16*)(ws + (48u << 20));      // 16 MiB  roped Q=K, frag layout
    bf16* Vhat = (bf16*)(ws + (64u << 20));      // 16 MiB  V, frag layout
    float2* rtab = (float2*)(ws + (80u << 20));  // 256 KiB cos/sin table
    bf16* AO   = xb;                             // alias: x consumed after gemm1

    cvt_kernel<<<8192, 256, 0, stream>>>(x, xb, 2097152);
    cvt_kernel<<<4096, 256, 0, stream>>>(wq, wqb, 1048576);
    cvt_kernel<<<4096, 256, 0, stream>>>(wo, wob, 1048576);
    rope_tab_kernel<<<128, 256, 0, stream>>>(rtab);

    gemm_bt<false><<<dim3(8, 8, 8), 256, 0, stream>>>(xb, wqb, Yb);
    conv_rope_kernel<<<dim3(4, 32, 8), 256, 0, stream>>>(Yb, wc, bc, Qhat, Vhat, rtab);
    attn_kernel<<<dim3(8, 8, 8), 256, 0, stream>>>(Qhat, Vhat, AO);
    gemm_bt<true><<<dim3(8, 8, 8), 256, 0, stream>>>(AO, wob, out);
}